// Round 1
// baseline (1149.757 us; speedup 1.0000x reference)
//
#include <hip/hip_runtime.h>

#define N_NODES 50000
#define N_EDGES 640000
#define D 128

// ---------------------------------------------------------------------------
// Kernel 1: Y = X @ W^T        X:[N,128] f32, W:[128,128] f32 (torch layout
// [out,in]), Y:[N,128] f32.  W^T staged in LDS (64 KiB). Each block processes
// 8 rows per iteration; 256 threads = 8 rows x 32 col-groups; each thread
// computes 4 consecutive output columns via float4 LDS reads (conflict-free:
// 32 lanes read consecutive 16B chunks of one sW row).
// ---------------------------------------------------------------------------
__global__ __launch_bounds__(256) void gemm_xWT(const float* __restrict__ X,
                                                const float* __restrict__ W,
                                                float* __restrict__ Y,
                                                int n) {
    __shared__ float sW[D][D];   // sW[d][o] = W[o][d]  (64 KiB)
    __shared__ float sA[8][D];   // 8 staged input rows (4 KiB)

    // Load W transposed into LDS (once per block). Write-side bank conflicts
    // are irrelevant: happens once, amortized over all block iterations.
    for (int i = threadIdx.x; i < D * D; i += 256) {
        int o = i >> 7;      // out index (row of W)
        int d = i & 127;     // in index  (col of W)
        sW[d][o] = W[i];
    }
    __syncthreads();

    const int t  = threadIdx.x;
    const int r  = t >> 5;        // local row 0..7
    const int cg = t & 31;        // col group (4 cols each)

    for (int base = blockIdx.x * 8; base < n; base += gridDim.x * 8) {
        // Stage 8 rows of X: each thread loads exactly one float4 (coalesced).
        const float4 xv = *reinterpret_cast<const float4*>(&X[(base + r) * D + cg * 4]);
        *reinterpret_cast<float4*>(&sA[r][cg * 4]) = xv;
        __syncthreads();

        float acc0 = 0.f, acc1 = 0.f, acc2 = 0.f, acc3 = 0.f;
        #pragma unroll 8
        for (int d = 0; d < D; ++d) {
            const float a = sA[r][d];  // broadcast within 32-lane group
            const float4 wv = *reinterpret_cast<const float4*>(&sW[d][cg * 4]);
            acc0 += a * wv.x;
            acc1 += a * wv.y;
            acc2 += a * wv.z;
            acc3 += a * wv.w;
        }
        *reinterpret_cast<float4*>(&Y[(base + r) * D + cg * 4]) =
            make_float4(acc0, acc1, acc2, acc3);
        __syncthreads();
    }
}

// ---------------------------------------------------------------------------
// Kernel 2: scatter-add  out[dst[e]] += ew[e] * Y[src[e]]
// 32 threads per edge; each thread handles 4 consecutive floats (float4
// gather, 4 scalar atomicAdds). Gather of a 512B row by 32 consecutive lanes
// is fully coalesced; Y (25.6 MB) is L3-resident.
// ---------------------------------------------------------------------------
__global__ __launch_bounds__(256) void scatter_edges(const float* __restrict__ Y,
                                                     const float* __restrict__ ew,
                                                     const int* __restrict__ src,
                                                     const int* __restrict__ dst,
                                                     float* __restrict__ out) {
    const unsigned tid = blockIdx.x * 256u + threadIdx.x;
    const unsigned e = tid >> 5;
    if (e >= N_EDGES) return;
    const int c = (tid & 31) * 4;

    const float w = ew[e];
    const int s = src[e];
    const int d = dst[e];

    const float4 v = *reinterpret_cast<const float4*>(&Y[s * D + c]);
    float* op = &out[d * D + c];
    atomicAdd(op + 0, v.x * w);
    atomicAdd(op + 1, v.y * w);
    atomicAdd(op + 2, v.z * w);
    atomicAdd(op + 3, v.w * w);
}

extern "C" void kernel_launch(void* const* d_in, const int* in_sizes, int n_in,
                              void* d_out, int out_size, void* d_ws, size_t ws_size,
                              hipStream_t stream) {
    const float* node_emb    = (const float*)d_in[0];  // [N, 128]
    const float* edge_weight = (const float*)d_in[1];  // [E]
    const int*   src         = (const int*)d_in[2];    // [E]
    const int*   dst         = (const int*)d_in[3];    // [E]
    const float* W           = (const float*)d_in[4];  // [128, 128] (out,in)

    float* out = (float*)d_out;                        // [N, 128]
    float* Y   = (float*)d_ws;                         // [N, 128] scratch

    // Zero the output (it is poisoned before timing and scatter accumulates).
    hipMemsetAsync(d_out, 0, (size_t)N_NODES * D * sizeof(float), stream);

    // Y = node_emb @ W^T   (linear layer commutes with the segment-sum)
    gemm_xWT<<<1024, 256, 0, stream>>>(node_emb, W, Y, N_NODES);

    // out[dst] += w * Y[src]
    const unsigned total_threads = N_EDGES * 32u;
    const unsigned blocks = (total_threads + 255u) / 256u;
    scatter_edges<<<blocks, 256, 0, stream>>>(Y, edge_weight, src, dst, out);
}

// Round 2
// 192.477 us; speedup vs baseline: 5.9735x; 5.9735x over previous
//
#include <hip/hip_runtime.h>

#define N_NODES 50000
#define N_EDGES 640000
#define D 128
#define NB ((N_NODES + 255) / 256)   // 196 scan blocks

// ---------------------------------------------------------------------------
// Kernel 1: Y = X @ W^T  (unchanged from round 1 — proven correct)
// ---------------------------------------------------------------------------
__global__ __launch_bounds__(256) void gemm_xWT(const float* __restrict__ X,
                                                const float* __restrict__ W,
                                                float* __restrict__ Y,
                                                int n) {
    __shared__ float sW[D][D];   // sW[d][o] = W[o][d]
    __shared__ float sA[8][D];

    for (int i = threadIdx.x; i < D * D; i += 256) {
        int o = i >> 7;
        int d = i & 127;
        sW[d][o] = W[i];
    }
    __syncthreads();

    const int t  = threadIdx.x;
    const int r  = t >> 5;
    const int cg = t & 31;

    for (int base = blockIdx.x * 8; base < n; base += gridDim.x * 8) {
        const float4 xv = *reinterpret_cast<const float4*>(&X[(base + r) * D + cg * 4]);
        *reinterpret_cast<float4*>(&sA[r][cg * 4]) = xv;
        __syncthreads();

        float acc0 = 0.f, acc1 = 0.f, acc2 = 0.f, acc3 = 0.f;
        #pragma unroll 8
        for (int d = 0; d < D; ++d) {
            const float a = sA[r][d];
            const float4 wv = *reinterpret_cast<const float4*>(&sW[d][cg * 4]);
            acc0 += a * wv.x;
            acc1 += a * wv.y;
            acc2 += a * wv.z;
            acc3 += a * wv.w;
        }
        *reinterpret_cast<float4*>(&Y[(base + r) * D + cg * 4]) =
            make_float4(acc0, acc1, acc2, acc3);
        __syncthreads();
    }
}

// ---------------------------------------------------------------------------
// Counting sort of edges by dst: hist -> scan (3 small kernels) -> place.
// ---------------------------------------------------------------------------
__global__ __launch_bounds__(256) void hist_kernel(const int* __restrict__ dst,
                                                   int* __restrict__ C) {
    int e = blockIdx.x * 256 + threadIdx.x;
    if (e < N_EDGES) atomicAdd(&C[dst[e]], 1);
}

__global__ __launch_bounds__(256) void scan1_kernel(const int* __restrict__ C,
                                                    int* __restrict__ O,
                                                    int* __restrict__ BS) {
    __shared__ int s[256];
    const int t = threadIdx.x;
    const int i = blockIdx.x * 256 + t;
    const int v = (i < N_NODES) ? C[i] : 0;
    s[t] = v;
    __syncthreads();
    for (int off = 1; off < 256; off <<= 1) {
        int add = (t >= off) ? s[t - off] : 0;
        __syncthreads();
        s[t] += add;
        __syncthreads();
    }
    if (i < N_NODES) O[i] = s[t] - v;           // block-local exclusive
    if (t == 255) BS[blockIdx.x] = s[255];      // block total
}

__global__ __launch_bounds__(256) void scan2_kernel(int* __restrict__ BS) {
    __shared__ int s[256];
    const int t = threadIdx.x;
    const int v = (t < NB) ? BS[t] : 0;
    s[t] = v;
    __syncthreads();
    for (int off = 1; off < 256; off <<= 1) {
        int add = (t >= off) ? s[t - off] : 0;
        __syncthreads();
        s[t] += add;
        __syncthreads();
    }
    if (t < NB) BS[t] = s[t] - v;               // exclusive block prefix
}

__global__ __launch_bounds__(256) void scan3_kernel(int* __restrict__ O,
                                                    int* __restrict__ C,
                                                    const int* __restrict__ BS) {
    const int i = blockIdx.x * 256 + threadIdx.x;
    if (i < N_NODES) {
        const int o = O[i] + BS[blockIdx.x];
        O[i] = o;
        C[i] = o;                                // cursor init = offsets
    }
    if (i == 0) O[N_NODES] = N_EDGES;
}

__global__ __launch_bounds__(256) void place_kernel(const int* __restrict__ src,
                                                    const int* __restrict__ dst,
                                                    const float* __restrict__ ew,
                                                    int* __restrict__ cursor,
                                                    int2* __restrict__ rec) {
    const int e = blockIdx.x * 256 + threadIdx.x;
    if (e >= N_EDGES) return;
    const int d = dst[e];
    const int pos = atomicAdd(&cursor[d], 1);
    rec[pos] = make_int2(src[e], __float_as_int(ew[e]));
}

// ---------------------------------------------------------------------------
// Aggregate: one wave (64 lanes) per destination node. Each lane owns 2
// consecutive output columns (float2 = 8B x 64 lanes = 512B row). Inner loop:
// 8B broadcast record load + 512B coalesced Y-row gather per edge, 4-deep
// unrolled for latency hiding. Writes every node exactly once (zeros for
// nodes with no in-edges) -> no d_out memset needed, no fp32 atomics at all.
// ---------------------------------------------------------------------------
__global__ __launch_bounds__(256) void aggregate_kernel(const float* __restrict__ Y,
                                                        const int2* __restrict__ rec,
                                                        const int* __restrict__ O,
                                                        float* __restrict__ out) {
    const int node = (blockIdx.x * 256 + threadIdx.x) >> 6;
    if (node >= N_NODES) return;
    const int lane = threadIdx.x & 63;
    const int beg = O[node];
    const int end = O[node + 1];

    float ax = 0.f, ay = 0.f;
    int i = beg;
    for (; i + 4 <= end; i += 4) {
        const int2 r0 = rec[i + 0];
        const int2 r1 = rec[i + 1];
        const int2 r2 = rec[i + 2];
        const int2 r3 = rec[i + 3];
        const float2 v0 = *reinterpret_cast<const float2*>(&Y[(size_t)r0.x * D + lane * 2]);
        const float2 v1 = *reinterpret_cast<const float2*>(&Y[(size_t)r1.x * D + lane * 2]);
        const float2 v2 = *reinterpret_cast<const float2*>(&Y[(size_t)r2.x * D + lane * 2]);
        const float2 v3 = *reinterpret_cast<const float2*>(&Y[(size_t)r3.x * D + lane * 2]);
        ax += __int_as_float(r0.y) * v0.x; ay += __int_as_float(r0.y) * v0.y;
        ax += __int_as_float(r1.y) * v1.x; ay += __int_as_float(r1.y) * v1.y;
        ax += __int_as_float(r2.y) * v2.x; ay += __int_as_float(r2.y) * v2.y;
        ax += __int_as_float(r3.y) * v3.x; ay += __int_as_float(r3.y) * v3.y;
    }
    for (; i < end; ++i) {
        const int2 r = rec[i];
        const float2 v = *reinterpret_cast<const float2*>(&Y[(size_t)r.x * D + lane * 2]);
        ax += __int_as_float(r.y) * v.x;
        ay += __int_as_float(r.y) * v.y;
    }
    *reinterpret_cast<float2*>(&out[(size_t)node * D + lane * 2]) = make_float2(ax, ay);
}

extern "C" void kernel_launch(void* const* d_in, const int* in_sizes, int n_in,
                              void* d_out, int out_size, void* d_ws, size_t ws_size,
                              hipStream_t stream) {
    const float* node_emb    = (const float*)d_in[0];  // [N, 128]
    const float* edge_weight = (const float*)d_in[1];  // [E]
    const int*   src         = (const int*)d_in[2];    // [E]
    const int*   dst         = (const int*)d_in[3];    // [E]
    const float* W           = (const float*)d_in[4];  // [128, 128]

    float* out = (float*)d_out;

    // Workspace layout (bytes):
    //   Y   @ 0           : 25,600,000  (N*128 f32)
    //   C   @ 25,600,000  : 200,000     (counts, then reused as cursor)
    //   O   @ 25,800,192  : 200,004     (offsets, N+1 ints)
    //   BS  @ 26,000,384  : 784         (block sums)
    //   REC @ 26,001,408  : 5,120,000   (sorted (src,w) records)
    // total ~31.1 MB
    char* ws = (char*)d_ws;
    float* Y   = (float*)ws;
    int*   C   = (int*)(ws + 25600000);
    int*   O   = (int*)(ws + 25800192);
    int*   BS  = (int*)(ws + 26000384);
    int2*  REC = (int2*)(ws + 26001408);

    hipMemsetAsync(C, 0, N_NODES * sizeof(int), stream);

    // Y = node_emb @ W^T (linear commutes with segment-sum)
    gemm_xWT<<<1024, 256, 0, stream>>>(node_emb, W, Y, N_NODES);

    // Counting sort of edges by dst
    hist_kernel <<<(N_EDGES + 255) / 256, 256, 0, stream>>>(dst, C);
    scan1_kernel<<<NB, 256, 0, stream>>>(C, O, BS);
    scan2_kernel<<<1, 256, 0, stream>>>(BS);
    scan3_kernel<<<NB, 256, 0, stream>>>(O, C, BS);
    place_kernel<<<(N_EDGES + 255) / 256, 256, 0, stream>>>(src, dst, edge_weight, C, REC);

    // Gather-aggregate per destination node (no fp32 atomics)
    aggregate_kernel<<<(N_NODES * 64 + 255) / 256, 256, 0, stream>>>(Y, REC, O, out);
}

// Round 3
// 139.852 us; speedup vs baseline: 8.2212x; 1.3763x over previous
//
#include <hip/hip_runtime.h>

#define N_NODES 50000
#define N_EDGES 640000
#define D 128
#define NB ((N_NODES + 255) / 256)   // scan blocks

// round-to-nearest-even f32 -> bf16
static __device__ __forceinline__ unsigned short f2bf(float f) {
    union { float f; unsigned u; } v; v.f = f;
    unsigned r = (v.u + 0x7FFFu + ((v.u >> 16) & 1u)) >> 16;
    return (unsigned short)r;
}

// ---------------------------------------------------------------------------
// Kernel 1: Ybf = bf16(X @ W^T).  64 rows x 128 cols per block, K chunked by
// 32. LDS = 24 KiB (sA 8K + sWt 16K) -> ~5 blocks/CU. Thread (rg,cg) computes
// an 8-row x 4-col register tile. Per 4-K-step: 8 broadcast b128 reads of sA
// (only 2 distinct addrs per wave -> conflict-free) + 4 b128 reads of sWt vs
// 128 FMAs -> VALU-bound. fp32 accumulate, bf16 store.
// ---------------------------------------------------------------------------
__global__ __launch_bounds__(256) void gemm_xWT_bf(const float* __restrict__ X,
                                                   const float* __restrict__ W,
                                                   unsigned short* __restrict__ Ybf) {
    __shared__ float sA[64][32];    // sA[r][k] = X[base+r][kc+k]
    __shared__ float sWt[32][128];  // sWt[k][o] = W[o][kc+k]

    const int t  = threadIdx.x;
    const int rg = t >> 5;          // 0..7  (8 rows each)
    const int cg = t & 31;          // 0..31 (4 cols each)
    const int base = blockIdx.x * 64;

    float acc[8][4];
    #pragma unroll
    for (int r = 0; r < 8; ++r)
        #pragma unroll
        for (int j = 0; j < 4; ++j) acc[r][j] = 0.f;

    const int arow = t >> 2;                      // 0..63
    const int acol = (t & 3) * 8;                 // 0,8,16,24
    const int grow = min(base + arow, N_NODES - 1);
    const int wo   = t >> 1;                      // 0..127
    const int wdh  = (t & 1) * 16;                // 0 or 16

    for (int kc = 0; kc < D; kc += 32) {
        // stage A chunk (coalesced float4 global reads)
        const float4 x0 = *reinterpret_cast<const float4*>(&X[(size_t)grow * D + kc + acol]);
        const float4 x1 = *reinterpret_cast<const float4*>(&X[(size_t)grow * D + kc + acol + 4]);
        *reinterpret_cast<float4*>(&sA[arow][acol])     = x0;
        *reinterpret_cast<float4*>(&sA[arow][acol + 4]) = x1;

        // stage W^T chunk: coalesced row reads, scalar transposed LDS writes
        const float4 w0 = *reinterpret_cast<const float4*>(&W[wo * D + kc + wdh + 0]);
        const float4 w1 = *reinterpret_cast<const float4*>(&W[wo * D + kc + wdh + 4]);
        const float4 w2 = *reinterpret_cast<const float4*>(&W[wo * D + kc + wdh + 8]);
        const float4 w3 = *reinterpret_cast<const float4*>(&W[wo * D + kc + wdh + 12]);
        sWt[wdh +  0][wo] = w0.x; sWt[wdh +  1][wo] = w0.y;
        sWt[wdh +  2][wo] = w0.z; sWt[wdh +  3][wo] = w0.w;
        sWt[wdh +  4][wo] = w1.x; sWt[wdh +  5][wo] = w1.y;
        sWt[wdh +  6][wo] = w1.z; sWt[wdh +  7][wo] = w1.w;
        sWt[wdh +  8][wo] = w2.x; sWt[wdh +  9][wo] = w2.y;
        sWt[wdh + 10][wo] = w2.z; sWt[wdh + 11][wo] = w2.w;
        sWt[wdh + 12][wo] = w3.x; sWt[wdh + 13][wo] = w3.y;
        sWt[wdh + 14][wo] = w3.z; sWt[wdh + 15][wo] = w3.w;
        __syncthreads();

        #pragma unroll
        for (int q = 0; q < 8; ++q) {
            const int d0 = q * 4;
            const float4 wv0 = *reinterpret_cast<const float4*>(&sWt[d0 + 0][cg * 4]);
            const float4 wv1 = *reinterpret_cast<const float4*>(&sWt[d0 + 1][cg * 4]);
            const float4 wv2 = *reinterpret_cast<const float4*>(&sWt[d0 + 2][cg * 4]);
            const float4 wv3 = *reinterpret_cast<const float4*>(&sWt[d0 + 3][cg * 4]);
            #pragma unroll
            for (int r = 0; r < 8; ++r) {
                const float4 av = *reinterpret_cast<const float4*>(&sA[rg * 8 + r][d0]);
                acc[r][0] += av.x * wv0.x; acc[r][0] += av.y * wv1.x;
                acc[r][0] += av.z * wv2.x; acc[r][0] += av.w * wv3.x;
                acc[r][1] += av.x * wv0.y; acc[r][1] += av.y * wv1.y;
                acc[r][1] += av.z * wv2.y; acc[r][1] += av.w * wv3.y;
                acc[r][2] += av.x * wv0.z; acc[r][2] += av.y * wv1.z;
                acc[r][2] += av.z * wv2.z; acc[r][2] += av.w * wv3.z;
                acc[r][3] += av.x * wv0.w; acc[r][3] += av.y * wv1.w;
                acc[r][3] += av.z * wv2.w; acc[r][3] += av.w * wv3.w;
            }
        }
        __syncthreads();
    }

    #pragma unroll
    for (int r = 0; r < 8; ++r) {
        const int row = base + rg * 8 + r;
        if (row < N_NODES) {
            const unsigned lo = (unsigned)f2bf(acc[r][0]) | ((unsigned)f2bf(acc[r][1]) << 16);
            const unsigned hi = (unsigned)f2bf(acc[r][2]) | ((unsigned)f2bf(acc[r][3]) << 16);
            *reinterpret_cast<uint2*>(&Ybf[(size_t)row * D + cg * 4]) = make_uint2(lo, hi);
        }
    }
}

// ---------------------------------------------------------------------------
// Counting sort of edges by dst (unchanged, proven correct).
// ---------------------------------------------------------------------------
__global__ __launch_bounds__(256) void hist_kernel(const int* __restrict__ dst,
                                                   int* __restrict__ C) {
    int e = blockIdx.x * 256 + threadIdx.x;
    if (e < N_EDGES) atomicAdd(&C[dst[e]], 1);
}

__global__ __launch_bounds__(256) void scan1_kernel(const int* __restrict__ C,
                                                    int* __restrict__ O,
                                                    int* __restrict__ BS) {
    __shared__ int s[256];
    const int t = threadIdx.x;
    const int i = blockIdx.x * 256 + t;
    const int v = (i < N_NODES) ? C[i] : 0;
    s[t] = v;
    __syncthreads();
    for (int off = 1; off < 256; off <<= 1) {
        int add = (t >= off) ? s[t - off] : 0;
        __syncthreads();
        s[t] += add;
        __syncthreads();
    }
    if (i < N_NODES) O[i] = s[t] - v;
    if (t == 255) BS[blockIdx.x] = s[255];
}

__global__ __launch_bounds__(256) void scan2_kernel(int* __restrict__ BS) {
    __shared__ int s[256];
    const int t = threadIdx.x;
    const int v = (t < NB) ? BS[t] : 0;
    s[t] = v;
    __syncthreads();
    for (int off = 1; off < 256; off <<= 1) {
        int add = (t >= off) ? s[t - off] : 0;
        __syncthreads();
        s[t] += add;
        __syncthreads();
    }
    if (t < NB) BS[t] = s[t] - v;
}

__global__ __launch_bounds__(256) void scan3_kernel(int* __restrict__ O,
                                                    int* __restrict__ C,
                                                    const int* __restrict__ BS) {
    const int i = blockIdx.x * 256 + threadIdx.x;
    if (i < N_NODES) {
        const int o = O[i] + BS[blockIdx.x];
        O[i] = o;
        C[i] = o;
    }
    if (i == 0) O[N_NODES] = N_EDGES;
}

__global__ __launch_bounds__(256) void place_kernel(const int* __restrict__ src,
                                                    const int* __restrict__ dst,
                                                    const float* __restrict__ ew,
                                                    int* __restrict__ cursor,
                                                    int2* __restrict__ rec) {
    const int e = blockIdx.x * 256 + threadIdx.x;
    if (e >= N_EDGES) return;
    const int d = dst[e];
    const int pos = atomicAdd(&cursor[d], 1);
    rec[pos] = make_int2(src[e], __float_as_int(ew[e]));
}

// ---------------------------------------------------------------------------
// Aggregate: one wave per node, 4 edges per iteration. Lane group g=lane>>4
// handles edge i+g; each of its 16 lanes loads 16B (8 bf16 cols). fp32
// accumulate; cross-group reduce via shfl_xor(16),(32); lanes 0..15 write the
// 512B fp32 output row. No fp32 atomics anywhere.
// ---------------------------------------------------------------------------
__global__ __launch_bounds__(256) void aggregate_bf(const unsigned short* __restrict__ Ybf,
                                                    const int2* __restrict__ rec,
                                                    const int* __restrict__ O,
                                                    float* __restrict__ out) {
    const int node = blockIdx.x * 4 + (threadIdx.x >> 6);
    if (node >= N_NODES) return;
    const int lane = threadIdx.x & 63;
    const int g = lane >> 4;          // edge sub-slot 0..3
    const int c = (lane & 15) * 8;    // 8 output cols
    const int beg = O[node];
    const int end = O[node + 1];

    float acc[8];
    #pragma unroll
    for (int k = 0; k < 8; ++k) acc[k] = 0.f;

    for (int i = beg; i < end; i += 4) {
        const int j  = i + g;
        const int jj = (j < end) ? j : (end - 1);
        const int2 r = rec[jj];
        const float w = (j < end) ? __int_as_float(r.y) : 0.f;
        const uint4 v = *reinterpret_cast<const uint4*>(&Ybf[(size_t)r.x * D + c]);
        acc[0] += w * __uint_as_float(v.x << 16);
        acc[1] += w * __uint_as_float(v.x & 0xFFFF0000u);
        acc[2] += w * __uint_as_float(v.y << 16);
        acc[3] += w * __uint_as_float(v.y & 0xFFFF0000u);
        acc[4] += w * __uint_as_float(v.z << 16);
        acc[5] += w * __uint_as_float(v.z & 0xFFFF0000u);
        acc[6] += w * __uint_as_float(v.w << 16);
        acc[7] += w * __uint_as_float(v.w & 0xFFFF0000u);
    }

    #pragma unroll
    for (int k = 0; k < 8; ++k) {
        acc[k] += __shfl_xor(acc[k], 16, 64);
        acc[k] += __shfl_xor(acc[k], 32, 64);
    }

    if (lane < 16) {
        *reinterpret_cast<float4*>(&out[(size_t)node * D + c + 0]) =
            make_float4(acc[0], acc[1], acc[2], acc[3]);
        *reinterpret_cast<float4*>(&out[(size_t)node * D + c + 4]) =
            make_float4(acc[4], acc[5], acc[6], acc[7]);
    }
}

extern "C" void kernel_launch(void* const* d_in, const int* in_sizes, int n_in,
                              void* d_out, int out_size, void* d_ws, size_t ws_size,
                              hipStream_t stream) {
    const float* node_emb    = (const float*)d_in[0];  // [N, 128]
    const float* edge_weight = (const float*)d_in[1];  // [E]
    const int*   src         = (const int*)d_in[2];    // [E]
    const int*   dst         = (const int*)d_in[3];    // [E]
    const float* W           = (const float*)d_in[4];  // [128, 128]

    float* out = (float*)d_out;

    // Workspace layout (bytes):
    //   Ybf @ 0           : 12,800,000  (N*128 bf16)
    //   C   @ 25,600,000  : 200,000
    //   O   @ 25,800,192  : 200,004
    //   BS  @ 26,000,384  : 784
    //   REC @ 26,001,408  : 5,120,000
    char* ws = (char*)d_ws;
    unsigned short* Ybf = (unsigned short*)ws;
    int*   C   = (int*)(ws + 25600000);
    int*   O   = (int*)(ws + 25800192);
    int*   BS  = (int*)(ws + 26000384);
    int2*  REC = (int2*)(ws + 26001408);

    hipMemsetAsync(C, 0, N_NODES * sizeof(int), stream);

    // Ybf = bf16(node_emb @ W^T)
    gemm_xWT_bf<<<(N_NODES + 63) / 64, 256, 0, stream>>>(node_emb, W, Ybf);

    // Counting sort of edges by dst
    hist_kernel <<<(N_EDGES + 255) / 256, 256, 0, stream>>>(dst, C);
    scan1_kernel<<<NB, 256, 0, stream>>>(C, O, BS);
    scan2_kernel<<<1, 256, 0, stream>>>(BS);
    scan3_kernel<<<NB, 256, 0, stream>>>(O, C, BS);
    place_kernel<<<(N_EDGES + 255) / 256, 256, 0, stream>>>(src, dst, edge_weight, C, REC);

    // Gather-aggregate per destination node
    aggregate_bf<<<(N_NODES + 3) / 4, 256, 0, stream>>>(Ybf, REC, O, out);
}

// Round 4
// 115.746 us; speedup vs baseline: 9.9335x; 1.2083x over previous
//
#include <hip/hip_runtime.h>

#define N_NODES 50000
#define N_EDGES 640000
#define D 128

// round-to-nearest-even f32 -> bf16
static __device__ __forceinline__ unsigned short f2bf(float f) {
    union { float f; unsigned u; } v; v.f = f;
    unsigned r = (v.u + 0x7FFFu + ((v.u >> 16) & 1u)) >> 16;
    return (unsigned short)r;
}

// ---------------------------------------------------------------------------
// Kernel 1: Ybf = bf16(X @ W^T).  64 rows x 128 cols per block, K chunked by
// 32. LDS = 24 KiB. Thread (rg,cg) computes an 8x4 register tile. (Proven
// correct in round 3.)
// ---------------------------------------------------------------------------
__global__ __launch_bounds__(256) void gemm_xWT_bf(const float* __restrict__ X,
                                                   const float* __restrict__ W,
                                                   unsigned short* __restrict__ Ybf) {
    __shared__ float sA[64][32];    // sA[r][k] = X[base+r][kc+k]
    __shared__ float sWt[32][128];  // sWt[k][o] = W[o][kc+k]

    const int t  = threadIdx.x;
    const int rg = t >> 5;
    const int cg = t & 31;
    const int base = blockIdx.x * 64;

    float acc[8][4];
    #pragma unroll
    for (int r = 0; r < 8; ++r)
        #pragma unroll
        for (int j = 0; j < 4; ++j) acc[r][j] = 0.f;

    const int arow = t >> 2;
    const int acol = (t & 3) * 8;
    const int grow = min(base + arow, N_NODES - 1);
    const int wo   = t >> 1;
    const int wdh  = (t & 1) * 16;

    for (int kc = 0; kc < D; kc += 32) {
        const float4 x0 = *reinterpret_cast<const float4*>(&X[(size_t)grow * D + kc + acol]);
        const float4 x1 = *reinterpret_cast<const float4*>(&X[(size_t)grow * D + kc + acol + 4]);
        *reinterpret_cast<float4*>(&sA[arow][acol])     = x0;
        *reinterpret_cast<float4*>(&sA[arow][acol + 4]) = x1;

        const float4 w0 = *reinterpret_cast<const float4*>(&W[wo * D + kc + wdh + 0]);
        const float4 w1 = *reinterpret_cast<const float4*>(&W[wo * D + kc + wdh + 4]);
        const float4 w2 = *reinterpret_cast<const float4*>(&W[wo * D + kc + wdh + 8]);
        const float4 w3 = *reinterpret_cast<const float4*>(&W[wo * D + kc + wdh + 12]);
        sWt[wdh +  0][wo] = w0.x; sWt[wdh +  1][wo] = w0.y;
        sWt[wdh +  2][wo] = w0.z; sWt[wdh +  3][wo] = w0.w;
        sWt[wdh +  4][wo] = w1.x; sWt[wdh +  5][wo] = w1.y;
        sWt[wdh +  6][wo] = w1.z; sWt[wdh +  7][wo] = w1.w;
        sWt[wdh +  8][wo] = w2.x; sWt[wdh +  9][wo] = w2.y;
        sWt[wdh + 10][wo] = w2.z; sWt[wdh + 11][wo] = w2.w;
        sWt[wdh + 12][wo] = w3.x; sWt[wdh + 13][wo] = w3.y;
        sWt[wdh + 14][wo] = w3.z; sWt[wdh + 15][wo] = w3.w;
        __syncthreads();

        #pragma unroll
        for (int q = 0; q < 8; ++q) {
            const int d0 = q * 4;
            const float4 wv0 = *reinterpret_cast<const float4*>(&sWt[d0 + 0][cg * 4]);
            const float4 wv1 = *reinterpret_cast<const float4*>(&sWt[d0 + 1][cg * 4]);
            const float4 wv2 = *reinterpret_cast<const float4*>(&sWt[d0 + 2][cg * 4]);
            const float4 wv3 = *reinterpret_cast<const float4*>(&sWt[d0 + 3][cg * 4]);
            #pragma unroll
            for (int r = 0; r < 8; ++r) {
                const float4 av = *reinterpret_cast<const float4*>(&sA[rg * 8 + r][d0]);
                acc[r][0] += av.x * wv0.x; acc[r][0] += av.y * wv1.x;
                acc[r][0] += av.z * wv2.x; acc[r][0] += av.w * wv3.x;
                acc[r][1] += av.x * wv0.y; acc[r][1] += av.y * wv1.y;
                acc[r][1] += av.z * wv2.y; acc[r][1] += av.w * wv3.y;
                acc[r][2] += av.x * wv0.z; acc[r][2] += av.y * wv1.z;
                acc[r][2] += av.z * wv2.z; acc[r][2] += av.w * wv3.z;
                acc[r][3] += av.x * wv0.w; acc[r][3] += av.y * wv1.w;
                acc[r][3] += av.z * wv2.w; acc[r][3] += av.w * wv3.w;
            }
        }
        __syncthreads();
    }

    #pragma unroll
    for (int r = 0; r < 8; ++r) {
        const int row = base + rg * 8 + r;
        if (row < N_NODES) {
            const unsigned lo = (unsigned)f2bf(acc[r][0]) | ((unsigned)f2bf(acc[r][1]) << 16);
            const unsigned hi = (unsigned)f2bf(acc[r][2]) | ((unsigned)f2bf(acc[r][3]) << 16);
            *reinterpret_cast<uint2*>(&Ybf[(size_t)row * D + cg * 4]) = make_uint2(lo, hi);
        }
    }
}

// ---------------------------------------------------------------------------
// Linked-list build (replaces memset+hist+scan1+scan2+scan3+place).
// 4 chains per node to keep 4-way edge parallelism in the aggregate.
// next[] stores are fully sequential/coalesced; 640K int atomics on an
// 800KB L2-resident head array.
// ---------------------------------------------------------------------------
__global__ __launch_bounds__(256) void zero_head(int4* __restrict__ head4) {
    const int i = blockIdx.x * 256 + threadIdx.x;
    if (i < N_NODES) head4[i] = make_int4(-1, -1, -1, -1);  // 4 chains = one int4
}

__global__ __launch_bounds__(256) void build_lists(const int* __restrict__ dst,
                                                   int* __restrict__ head,
                                                   int* __restrict__ next) {
    const int e = blockIdx.x * 256 + threadIdx.x;
    if (e >= N_EDGES) return;
    const int d = dst[e];
    const int old = atomicExch(&head[d * 4 + (e & 3)], e);
    next[e] = old;
}

// ---------------------------------------------------------------------------
// Aggregate: one wave per node; lane group g = lane>>4 chases chain g.
// All 16 lanes of a group share e (broadcast loads). next[e] is issued
// before the row gather so the serial chain costs ~1 L2 hit per hop.
// fp32 accumulate, shfl_xor(16/32) cross-group reduce, one 512B row write
// per node. Zero-edge nodes write zeros (no d_out memset needed).
// ---------------------------------------------------------------------------
__global__ __launch_bounds__(256) void aggregate_list(const unsigned short* __restrict__ Ybf,
                                                      const int* __restrict__ src,
                                                      const float* __restrict__ ew,
                                                      const int* __restrict__ head,
                                                      const int* __restrict__ next,
                                                      float* __restrict__ out) {
    const int node = blockIdx.x * 4 + (threadIdx.x >> 6);
    if (node >= N_NODES) return;
    const int lane = threadIdx.x & 63;
    const int g = lane >> 4;          // chain 0..3
    const int c = (lane & 15) * 8;    // 8 output cols

    float acc[8];
    #pragma unroll
    for (int k = 0; k < 8; ++k) acc[k] = 0.f;

    int e = head[node * 4 + g];
    while (e >= 0) {
        const int en  = next[e];      // issue the chase load first
        const float w = ew[e];
        const int  s  = src[e];
        const uint4 v = *reinterpret_cast<const uint4*>(&Ybf[(size_t)s * D + c]);
        acc[0] += w * __uint_as_float(v.x << 16);
        acc[1] += w * __uint_as_float(v.x & 0xFFFF0000u);
        acc[2] += w * __uint_as_float(v.y << 16);
        acc[3] += w * __uint_as_float(v.y & 0xFFFF0000u);
        acc[4] += w * __uint_as_float(v.z << 16);
        acc[5] += w * __uint_as_float(v.z & 0xFFFF0000u);
        acc[6] += w * __uint_as_float(v.w << 16);
        acc[7] += w * __uint_as_float(v.w & 0xFFFF0000u);
        e = en;
    }

    #pragma unroll
    for (int k = 0; k < 8; ++k) {
        acc[k] += __shfl_xor(acc[k], 16, 64);
        acc[k] += __shfl_xor(acc[k], 32, 64);
    }

    if (lane < 16) {
        *reinterpret_cast<float4*>(&out[(size_t)node * D + c + 0]) =
            make_float4(acc[0], acc[1], acc[2], acc[3]);
        *reinterpret_cast<float4*>(&out[(size_t)node * D + c + 4]) =
            make_float4(acc[4], acc[5], acc[6], acc[7]);
    }
}

extern "C" void kernel_launch(void* const* d_in, const int* in_sizes, int n_in,
                              void* d_out, int out_size, void* d_ws, size_t ws_size,
                              hipStream_t stream) {
    const float* node_emb    = (const float*)d_in[0];  // [N, 128]
    const float* edge_weight = (const float*)d_in[1];  // [E]
    const int*   src         = (const int*)d_in[2];    // [E]
    const int*   dst         = (const int*)d_in[3];    // [E]
    const float* W           = (const float*)d_in[4];  // [128, 128]

    float* out = (float*)d_out;

    // Workspace layout (bytes):
    //   Ybf  @ 0          : 12,800,000  (N*128 bf16)
    //   head @ 12,800,000 :    800,000  (4 chains per node, int)
    //   next @ 13,600,000 :  2,560,000  (E ints)
    // total ~16.2 MB
    char* ws = (char*)d_ws;
    unsigned short* Ybf  = (unsigned short*)ws;
    int*            head = (int*)(ws + 12800000);
    int*            next = (int*)(ws + 13600000);

    // Ybf = bf16(node_emb @ W^T)   (linear commutes with segment-sum)
    gemm_xWT_bf<<<(N_NODES + 63) / 64, 256, 0, stream>>>(node_emb, W, Ybf);

    // Per-node 4-way linked lists over edges
    zero_head  <<<(N_NODES + 255) / 256, 256, 0, stream>>>((int4*)head);
    build_lists<<<(N_EDGES + 255) / 256, 256, 0, stream>>>(dst, head, next);

    // Gather-aggregate per destination node
    aggregate_list<<<(N_NODES + 3) / 4, 256, 0, stream>>>(Ybf, src, edge_weight, head, next, out);
}